// Round 1
// baseline (199.871 us; speedup 1.0000x reference)
//
#include <hip/hip_runtime.h>
#include <hip/hip_bf16.h>

typedef __bf16 bf16;
typedef bf16 bf16x8 __attribute__((ext_vector_type(8)));
typedef float f32x4 __attribute__((ext_vector_type(4)));

#define GLOAD16(g, l) __builtin_amdgcn_global_load_lds( \
    (const __attribute__((address_space(1))) void*)(g),  \
    (__attribute__((address_space(3))) void*)(l), 16, 0, 0)

// ---------------- cast fp32 -> bf16, 8 elems/thread ----------------
__global__ __launch_bounds__(256) void cast_f32_bf16(const float* __restrict__ in,
                                                     bf16* __restrict__ out, int n8) {
  int i = blockIdx.x * 256 + threadIdx.x;
  if (i >= n8) return;
  const float4* p = (const float4*)in + (size_t)i * 2;
  float4 a = p[0], b = p[1];
  bf16x8 o;
  o[0] = (bf16)a.x; o[1] = (bf16)a.y; o[2] = (bf16)a.z; o[3] = (bf16)a.w;
  o[4] = (bf16)b.x; o[5] = (bf16)b.y; o[6] = (bf16)b.z; o[7] = (bf16)b.w;
  ((bf16x8*)out)[i] = o;
}

// ------------- transpose+cast: src[K][N] f32 -> dst[N][K] bf16 -------------
__global__ __launch_bounds__(256) void transpose_cast(const float* __restrict__ src,
                                                      bf16* __restrict__ dst,
                                                      int K, int N) {
  __shared__ float tile[32][33];
  int n0 = blockIdx.x * 32, k0 = blockIdx.y * 32;
  int tx = threadIdx.x, ty = threadIdx.y;  // 32 x 8
#pragma unroll
  for (int i = 0; i < 4; i++)
    tile[ty + 8 * i][tx] = src[(size_t)(k0 + ty + 8 * i) * N + n0 + tx];
  __syncthreads();
#pragma unroll
  for (int i = 0; i < 4; i++)
    dst[(size_t)(n0 + ty + 8 * i) * K + k0 + tx] = (bf16)tile[tx][ty + 8 * i];
}

// ---------------- GEMM mainloop: C[128,128] += A[M,K] * Bt[N,K]^T ----------
// m97 structure: BK=32, 4 waves (2x2), each wave 64x64 = 4x4 frags of 16x16x32.
__device__ __forceinline__ void gemm_mainloop(const bf16* __restrict__ A,
                                              const bf16* __restrict__ Bt,
                                              int K, int m0, int n0,
                                              f32x4 acc[4][4],
                                              bf16* As, bf16* Bs) {
  int tid = threadIdx.x;
  int lane = tid & 63;
  int wave = tid >> 6;
  int wr = wave >> 1, wc = wave & 1;
  f32x4 z = {0.f, 0.f, 0.f, 0.f};
#pragma unroll
  for (int m = 0; m < 4; m++)
#pragma unroll
    for (int n = 0; n < 4; n++) acc[m][n] = z;
  int c16 = lane & 15;
  int ks8 = (lane >> 4) * 8;
  for (int k0 = 0; k0 < K; k0 += 32) {
#pragma unroll
    for (int i = 0; i < 2; i++) {
      int c = tid + i * 256;               // 0..511, lane-consecutive per wave
      int r = c >> 2, ks = (c & 3) * 8;
      GLOAD16(A + (size_t)(m0 + r) * K + k0 + ks, As + c * 8);
    }
#pragma unroll
    for (int i = 0; i < 2; i++) {
      int c = tid + i * 256;
      int r = c >> 2, ks = (c & 3) * 8;
      GLOAD16(Bt + (size_t)(n0 + r) * K + k0 + ks, Bs + c * 8);
    }
    __syncthreads();
    bf16x8 af[4], bfr[4];
#pragma unroll
    for (int m = 0; m < 4; m++)
      af[m] = *(const bf16x8*)(As + (wr * 64 + m * 16 + c16) * 32 + ks8);
#pragma unroll
    for (int n = 0; n < 4; n++)
      bfr[n] = *(const bf16x8*)(Bs + (wc * 64 + n * 16 + c16) * 32 + ks8);
#pragma unroll
    for (int m = 0; m < 4; m++)
#pragma unroll
      for (int n = 0; n < 4; n++)
        acc[m][n] = __builtin_amdgcn_mfma_f32_16x16x32_bf16(af[m], bfr[n], acc[m][n], 0, 0, 0);
    __syncthreads();
  }
}

// ---- QKV GEMM: x[4096,1024] @ WqkvT[3072,1024]^T -> q,k scaled/vT scatter ----
__global__ __launch_bounds__(256) void gemm_qkv(const bf16* __restrict__ A,
                                                const bf16* __restrict__ Bt,
                                                bf16* __restrict__ q,
                                                bf16* __restrict__ kk,
                                                bf16* __restrict__ vt) {
  __shared__ bf16 As[128 * 32];
  __shared__ bf16 Bs[128 * 32];
  int m0 = blockIdx.y * 128, n0 = blockIdx.x * 128;
  f32x4 acc[4][4];
  gemm_mainloop(A, Bt, 1024, m0, n0, acc, As, Bs);
  int lane = threadIdx.x & 63;
  int wave = threadIdx.x >> 6;
  int wr = wave >> 1, wc = wave & 1;
  int which = n0 >> 10;  // 0=q 1=k 2=v, block-uniform (128 | 1024)
#pragma unroll
  for (int m = 0; m < 4; m++)
#pragma unroll
    for (int n = 0; n < 4; n++)
#pragma unroll
      for (int j = 0; j < 4; j++) {
        int gm = m0 + wr * 64 + m * 16 + (lane >> 4) * 4 + j;
        int gn = n0 + wc * 64 + n * 16 + (lane & 15);
        int rem = gn & 1023;
        int h = rem >> 6, d = rem & 63;
        int b = gm >> 11, t = gm & 2047;
        float v = acc[m][n][j];
        size_t bh = (size_t)(b * 16 + h);
        if (which == 0)      q[(bh * 2048 + t) * 64 + d]  = (bf16)(v * 0.125f);
        else if (which == 1) kk[(bh * 2048 + t) * 64 + d] = (bf16)v;
        else                 vt[(bh * 64 + d) * 2048 + t] = (bf16)v;
      }
}

// ---- final GEMM: attn[4096,1024] @ WoutT[1024,1024]^T -> out fp32 ----
__global__ __launch_bounds__(256) void gemm_out(const bf16* __restrict__ A,
                                                const bf16* __restrict__ Bt,
                                                float* __restrict__ C) {
  __shared__ bf16 As[128 * 32];
  __shared__ bf16 Bs[128 * 32];
  int m0 = blockIdx.y * 128, n0 = blockIdx.x * 128;
  f32x4 acc[4][4];
  gemm_mainloop(A, Bt, 1024, m0, n0, acc, As, Bs);
  int lane = threadIdx.x & 63;
  int wave = threadIdx.x >> 6;
  int wr = wave >> 1, wc = wave & 1;
#pragma unroll
  for (int m = 0; m < 4; m++)
#pragma unroll
    for (int n = 0; n < 4; n++)
#pragma unroll
      for (int j = 0; j < 4; j++) {
        int gm = m0 + wr * 64 + m * 16 + (lane >> 4) * 4 + j;
        int gn = n0 + wc * 64 + n * 16 + (lane & 15);
        C[(size_t)gm * 1024 + gn] = acc[m][n][j];
      }
}

// ---------------- flash attention ----------------
// grid (16 qtiles, 32 bh). Block 256 thr = 4 waves; wave w owns q rows
// [q0+32w, q0+32w+32). Key tiles of 64. q pre-scaled by 1/8.
__global__ __launch_bounds__(256) void attn(const bf16* __restrict__ q,
                                            const bf16* __restrict__ kk,
                                            const bf16* __restrict__ vt,
                                            bf16* __restrict__ out) {
  __shared__ bf16 Qs[128 * 64];   // 16 KB
  __shared__ bf16 Ks[64 * 64];    // 8 KB  (chunk-XOR swizzled)
  __shared__ bf16 Vs[64 * 64];    // 8 KB  (chunk-XOR swizzled)
  __shared__ bf16 Ps[4 * 32 * 72];// 18 KB (pitch 72 kills bank conflicts)
  int tid = threadIdx.x, lane = tid & 63, w = tid >> 6;
  int c16 = lane & 15, g = lane >> 4;
  int q0 = blockIdx.x * 128;
  int bh = blockIdx.y;
  const bf16* qb = q  + (size_t)bh * 2048 * 64;
  const bf16* kb = kk + (size_t)bh * 2048 * 64;
  const bf16* vb = vt + (size_t)bh * 64 * 2048;

  // stage Q tile [128][64]
#pragma unroll
  for (int i = 0; i < 4; i++) {
    int c = tid + i * 256;             // 0..1023
    int r = c >> 3, ds = (c & 7) * 8;
    GLOAD16(qb + (size_t)(q0 + r) * 64 + ds, Qs + c * 8);
  }
  __syncthreads();
  bf16x8 qf[2][2];
#pragma unroll
  for (int m = 0; m < 2; m++)
#pragma unroll
    for (int ks = 0; ks < 2; ks++)
      qf[m][ks] = *(const bf16x8*)(Qs + (w * 32 + m * 16 + c16) * 64 + ks * 32 + g * 8);

  f32x4 o[2][4];
  float mrun[2][4], lrun[2][4];
  {
    f32x4 z = {0.f, 0.f, 0.f, 0.f};
#pragma unroll
    for (int m = 0; m < 2; m++) {
#pragma unroll
      for (int n = 0; n < 4; n++) o[m][n] = z;
#pragma unroll
      for (int j = 0; j < 4; j++) { mrun[m][j] = -__builtin_inff(); lrun[m][j] = 0.f; }
    }
  }
  int qmax = q0 + w * 32 + 31;
  bf16* Pw = Ps + w * 32 * 72;

  for (int s0 = 0; s0 < q0 + 128; s0 += 64) {
    __syncthreads();   // prior tile's K/V reads done
    // stage K tile [64 s][64 d], source pre-swizzled so linear LDS is swizzled
#pragma unroll
    for (int i = 0; i < 2; i++) {
      int c = tid + i * 256;
      int r = c >> 3, p = c & 7;
      GLOAD16(kb + (size_t)(s0 + r) * 64 + ((p ^ (r & 7)) * 8), Ks + c * 8);
    }
    // stage V tile [64 d][64 s] from vT
#pragma unroll
    for (int i = 0; i < 2; i++) {
      int c = tid + i * 256;
      int r = c >> 3, p = c & 7;
      GLOAD16(vb + (size_t)r * 2048 + s0 + ((p ^ (r & 7)) * 8), Vs + c * 8);
    }
    __syncthreads();
    if (s0 <= qmax) {   // wave-uniform causal skip (no barriers inside)
      // ---- QK^T ----
      f32x4 s[2][4];
      {
        f32x4 z = {0.f, 0.f, 0.f, 0.f};
#pragma unroll
        for (int m = 0; m < 2; m++)
#pragma unroll
          for (int n = 0; n < 4; n++) s[m][n] = z;
      }
#pragma unroll
      for (int ks = 0; ks < 2; ks++) {
        bf16x8 kf[4];
#pragma unroll
        for (int n = 0; n < 4; n++) {
          int srow = n * 16 + c16;
          kf[n] = *(const bf16x8*)((const char*)Ks + srow * 128 +
                                   (((ks * 4 + g) ^ (srow & 7)) << 4));
        }
#pragma unroll
        for (int m = 0; m < 2; m++)
#pragma unroll
          for (int n = 0; n < 4; n++)
            s[m][n] = __builtin_amdgcn_mfma_f32_16x16x32_bf16(qf[m][ks], kf[n], s[m][n], 0, 0, 0);
      }
      // ---- causal mask ----
#pragma unroll
      for (int m = 0; m < 2; m++)
#pragma unroll
        for (int n = 0; n < 4; n++)
#pragma unroll
          for (int j = 0; j < 4; j++) {
            int qr = q0 + w * 32 + m * 16 + g * 4 + j;
            int sc = s0 + n * 16 + c16;
            if (sc > qr) s[m][n][j] = -__builtin_inff();
          }
      // ---- online softmax (row lives in 16-lane group) ----
#pragma unroll
      for (int m = 0; m < 2; m++)
#pragma unroll
        for (int j = 0; j < 4; j++) {
          float t = fmaxf(fmaxf(s[m][0][j], s[m][1][j]), fmaxf(s[m][2][j], s[m][3][j]));
#pragma unroll
          for (int off = 1; off < 16; off <<= 1) t = fmaxf(t, __shfl_xor(t, off, 16));
          float mnew = fmaxf(mrun[m][j], t);
          float corr = __expf(mrun[m][j] - mnew);
          float p0 = __expf(s[m][0][j] - mnew);
          float p1 = __expf(s[m][1][j] - mnew);
          float p2 = __expf(s[m][2][j] - mnew);
          float p3 = __expf(s[m][3][j] - mnew);
          float rsum = (p0 + p1) + (p2 + p3);
#pragma unroll
          for (int off = 1; off < 16; off <<= 1) rsum += __shfl_xor(rsum, off, 16);
#pragma unroll
          for (int n = 0; n < 4; n++) o[m][n][j] *= corr;
          lrun[m][j] = lrun[m][j] * corr + rsum;
          mrun[m][j] = mnew;
          int prow = m * 16 + g * 4 + j;
          Pw[prow * 72 + 0 * 16 + c16] = (bf16)p0;
          Pw[prow * 72 + 1 * 16 + c16] = (bf16)p1;
          Pw[prow * 72 + 2 * 16 + c16] = (bf16)p2;
          Pw[prow * 72 + 3 * 16 + c16] = (bf16)p3;
        }
      // ---- PV (per-wave P region: lgkmcnt ordering suffices, no barrier) ----
#pragma unroll
      for (int ks = 0; ks < 2; ks++) {
        bf16x8 pf[2], vf[4];
#pragma unroll
        for (int m = 0; m < 2; m++)
          pf[m] = *(const bf16x8*)(Pw + (m * 16 + c16) * 72 + ks * 32 + g * 8);
#pragma unroll
        for (int n = 0; n < 4; n++) {
          int drow = n * 16 + c16;
          vf[n] = *(const bf16x8*)((const char*)Vs + drow * 128 +
                                   (((ks * 4 + g) ^ (drow & 7)) << 4));
        }
#pragma unroll
        for (int m = 0; m < 2; m++)
#pragma unroll
          for (int n = 0; n < 4; n++)
            o[m][n] = __builtin_amdgcn_mfma_f32_16x16x32_bf16(pf[m], vf[n], o[m][n], 0, 0, 0);
      }
    }
  }
  // ---- epilogue: out[b*2048+t][h*64+d] bf16 ----
  int b = bh >> 4, h = bh & 15;
#pragma unroll
  for (int m = 0; m < 2; m++)
#pragma unroll
    for (int j = 0; j < 4; j++) {
      float inv = 1.f / lrun[m][j];
      int t = q0 + w * 32 + m * 16 + g * 4 + j;
#pragma unroll
      for (int n = 0; n < 4; n++) {
        int col = h * 64 + n * 16 + c16;
        out[((size_t)(b * 2048 + t)) * 1024 + col] = (bf16)(o[m][n][j] * inv);
      }
    }
}

extern "C" void kernel_launch(void* const* d_in, const int* in_sizes, int n_in,
                              void* d_out, int out_size, void* d_ws, size_t ws_size,
                              hipStream_t stream) {
  const float* x    = (const float*)d_in[0];
  const float* Wqkv = (const float*)d_in[1];
  const float* Wout = (const float*)d_in[2];
  float* outp = (float*)d_out;
  char* ws = (char*)d_ws;
  const size_t MB = 1024 * 1024;
  bf16* xb    = (bf16*)(ws);             // 8 MB [4096][1024]; later reused as attn out
  bf16* wqkvT = (bf16*)(ws + 8 * MB);    // 6 MB [3072][1024]
  bf16* woutT = (bf16*)(ws + 14 * MB);   // 2 MB [1024][1024]
  bf16* qb    = (bf16*)(ws + 16 * MB);   // 8 MB [32][2048][64] (pre-scaled 1/8)
  bf16* kb    = (bf16*)(ws + 24 * MB);   // 8 MB [32][2048][64]
  bf16* vtb   = (bf16*)(ws + 32 * MB);   // 8 MB [32][64][2048]

  hipLaunchKernelGGL(cast_f32_bf16, dim3(2048), dim3(256), 0, stream,
                     x, xb, 4096 * 1024 / 8);
  hipLaunchKernelGGL(transpose_cast, dim3(96, 32), dim3(32, 8), 0, stream,
                     Wqkv, wqkvT, 1024, 3072);
  hipLaunchKernelGGL(transpose_cast, dim3(32, 32), dim3(32, 8), 0, stream,
                     Wout, woutT, 1024, 1024);
  hipLaunchKernelGGL(gemm_qkv, dim3(24, 32), dim3(256), 0, stream,
                     xb, wqkvT, qb, kb, vtb);
  hipLaunchKernelGGL(attn, dim3(16, 32), dim3(256), 0, stream,
                     qb, kb, vtb, xb);
  hipLaunchKernelGGL(gemm_out, dim3(8, 32), dim3(256), 0, stream,
                     xb, woutT, outp);
}

// Round 2
// 148.081 us; speedup vs baseline: 1.3497x; 1.3497x over previous
//
#include <hip/hip_runtime.h>
#include <hip/hip_bf16.h>

typedef __bf16 bf16;
typedef bf16 bf16x4 __attribute__((ext_vector_type(4)));
typedef bf16 bf16x8 __attribute__((ext_vector_type(8)));
typedef float f32x4 __attribute__((ext_vector_type(4)));

#define GLOAD16(g, l) __builtin_amdgcn_global_load_lds( \
    (const __attribute__((address_space(1))) void*)(g),  \
    (__attribute__((address_space(3))) void*)(l), 16, 0, 0)

// ---------------- cast fp32 -> bf16, 8 elems/thread ----------------
__global__ __launch_bounds__(256) void cast_f32_bf16(const float* __restrict__ in,
                                                     bf16* __restrict__ out, int n8) {
  int i = blockIdx.x * 256 + threadIdx.x;
  if (i >= n8) return;
  const float4* p = (const float4*)in + (size_t)i * 2;
  float4 a = p[0], b = p[1];
  bf16x8 o;
  o[0] = (bf16)a.x; o[1] = (bf16)a.y; o[2] = (bf16)a.z; o[3] = (bf16)a.w;
  o[4] = (bf16)b.x; o[5] = (bf16)b.y; o[6] = (bf16)b.z; o[7] = (bf16)b.w;
  ((bf16x8*)out)[i] = o;
}

// ------------- transpose+cast: src[K][N] f32 -> dst[N][K] bf16 -------------
__global__ __launch_bounds__(256) void transpose_cast(const float* __restrict__ src,
                                                      bf16* __restrict__ dst,
                                                      int K, int N) {
  __shared__ float tile[32][33];
  int n0 = blockIdx.x * 32, k0 = blockIdx.y * 32;
  int tx = threadIdx.x, ty = threadIdx.y;  // 32 x 8
#pragma unroll
  for (int i = 0; i < 4; i++)
    tile[ty + 8 * i][tx] = src[(size_t)(k0 + ty + 8 * i) * N + n0 + tx];
  __syncthreads();
#pragma unroll
  for (int i = 0; i < 4; i++)
    dst[(size_t)(n0 + ty + 8 * i) * K + k0 + tx] = (bf16)tile[tx][ty + 8 * i];
}

// ---------------- GEMM mainloop: C[128,128] += A[M,K] * Bt[N,K]^T ----------
__device__ __forceinline__ void gemm_mainloop(const bf16* __restrict__ A,
                                              const bf16* __restrict__ Bt,
                                              int K, int m0, int n0,
                                              f32x4 acc[4][4],
                                              bf16* As, bf16* Bs) {
  int tid = threadIdx.x;
  int lane = tid & 63;
  int wave = tid >> 6;
  int wr = wave >> 1, wc = wave & 1;
  f32x4 z = {0.f, 0.f, 0.f, 0.f};
#pragma unroll
  for (int m = 0; m < 4; m++)
#pragma unroll
    for (int n = 0; n < 4; n++) acc[m][n] = z;
  int c16 = lane & 15;
  int ks8 = (lane >> 4) * 8;
  for (int k0 = 0; k0 < K; k0 += 32) {
#pragma unroll
    for (int i = 0; i < 2; i++) {
      int c = tid + i * 256;
      int r = c >> 2, ks = (c & 3) * 8;
      GLOAD16(A + (size_t)(m0 + r) * K + k0 + ks, As + c * 8);
    }
#pragma unroll
    for (int i = 0; i < 2; i++) {
      int c = tid + i * 256;
      int r = c >> 2, ks = (c & 3) * 8;
      GLOAD16(Bt + (size_t)(n0 + r) * K + k0 + ks, Bs + c * 8);
    }
    __syncthreads();
    bf16x8 af[4], bfr[4];
#pragma unroll
    for (int m = 0; m < 4; m++)
      af[m] = *(const bf16x8*)(As + (wr * 64 + m * 16 + c16) * 32 + ks8);
#pragma unroll
    for (int n = 0; n < 4; n++)
      bfr[n] = *(const bf16x8*)(Bs + (wc * 64 + n * 16 + c16) * 32 + ks8);
#pragma unroll
    for (int m = 0; m < 4; m++)
#pragma unroll
      for (int n = 0; n < 4; n++)
        acc[m][n] = __builtin_amdgcn_mfma_f32_16x16x32_bf16(af[m], bfr[n], acc[m][n], 0, 0, 0);
    __syncthreads();
  }
}

// ---- QKV GEMM: x[4096,1024] @ WqkvT[3072,1024]^T -> q,k scaled / vT scatter ----
__global__ __launch_bounds__(256) void gemm_qkv(const bf16* __restrict__ A,
                                                const bf16* __restrict__ Bt,
                                                bf16* __restrict__ q,
                                                bf16* __restrict__ kk,
                                                bf16* __restrict__ vt) {
  __shared__ bf16 As[128 * 32];
  __shared__ bf16 Bs[128 * 32];
  int m0 = blockIdx.y * 128, n0 = blockIdx.x * 128;
  f32x4 acc[4][4];
  gemm_mainloop(A, Bt, 1024, m0, n0, acc, As, Bs);
  int lane = threadIdx.x & 63;
  int wave = threadIdx.x >> 6;
  int wr = wave >> 1, wc = wave & 1;
  int which = n0 >> 10;
#pragma unroll
  for (int m = 0; m < 4; m++)
#pragma unroll
    for (int n = 0; n < 4; n++)
#pragma unroll
      for (int j = 0; j < 4; j++) {
        int gm = m0 + wr * 64 + m * 16 + (lane >> 4) * 4 + j;
        int gn = n0 + wc * 64 + n * 16 + (lane & 15);
        int rem = gn & 1023;
        int h = rem >> 6, d = rem & 63;
        int b = gm >> 11, t = gm & 2047;
        float v = acc[m][n][j];
        size_t bh = (size_t)(b * 16 + h);
        if (which == 0)      q[(bh * 2048 + t) * 64 + d]  = (bf16)(v * 0.125f);
        else if (which == 1) kk[(bh * 2048 + t) * 64 + d] = (bf16)v;
        else                 vt[(bh * 64 + d) * 2048 + t] = (bf16)v;
      }
}

// ---- final GEMM: attn[4096,1024] @ WoutT[1024,1024]^T -> out fp32 ----
__global__ __launch_bounds__(256) void gemm_out(const bf16* __restrict__ A,
                                                const bf16* __restrict__ Bt,
                                                float* __restrict__ C) {
  __shared__ bf16 As[128 * 32];
  __shared__ bf16 Bs[128 * 32];
  int m0 = blockIdx.y * 128, n0 = blockIdx.x * 128;
  f32x4 acc[4][4];
  gemm_mainloop(A, Bt, 1024, m0, n0, acc, As, Bs);
  int lane = threadIdx.x & 63;
  int wave = threadIdx.x >> 6;
  int wr = wave >> 1, wc = wave & 1;
#pragma unroll
  for (int m = 0; m < 4; m++)
#pragma unroll
    for (int n = 0; n < 4; n++)
#pragma unroll
      for (int j = 0; j < 4; j++) {
        int gm = m0 + wr * 64 + m * 16 + (lane >> 4) * 4 + j;
        int gn = n0 + wc * 64 + n * 16 + (lane & 15);
        C[(size_t)gm * 1024 + gn] = acc[m][n][j];
      }
}

// ---------------- flash attention (swapped-QK^T, dbuf K/V) ----------------
// grid (16 qtiles, 32 bh), 256 thr = 4 waves; wave w owns q rows [q0+32w, +32).
// Swapped QK^T: S^T = mfma(K, Q) -> lane holds 16 s-values for q = c16 per
// m-block; softmax = in-reg + 2 shuffles. P packed to LDS (XOR-swizzled) to
// feed PV A-frags as ds_read_b128. K/V double-buffered (stage t+1 issued
// before compute t; barrier drains it after compute).
__global__ __launch_bounds__(256) void attn(const bf16* __restrict__ q,
                                            const bf16* __restrict__ kk,
                                            const bf16* __restrict__ vt,
                                            bf16* __restrict__ out) {
  __shared__ bf16 Ks[2][64 * 64];   // 16 KB (chunk-XOR swizzled)
  __shared__ bf16 Vs[2][64 * 64];   // 16 KB (chunk-XOR swizzled)
  __shared__ bf16 PQ[128 * 64];     // 16 KB: Q staging (prologue) / P tiles (loop)
  int tid = threadIdx.x, lane = tid & 63, w = tid >> 6;
  int c16 = lane & 15, g = lane >> 4, g4 = g * 4;
  int bh = blockIdx.y;
  // pair-balance: co-resident blocks (id, id+256) = (bx, bh) & (bx, bh+16);
  // flip bx for bh>=16 so each pair's tile counts sum to a constant.
  int bx = (bh & 16) ? (15 - (int)blockIdx.x) : (int)blockIdx.x;
  int q0 = bx * 128;
  const bf16* qb = q  + (size_t)bh * 2048 * 64;
  const bf16* kb = kk + (size_t)bh * 2048 * 64;
  const bf16* vb = vt + (size_t)bh * 64 * 2048;

  // ---- prologue: stage Q[128][64] and K/V tile 0 ----
#pragma unroll
  for (int i = 0; i < 4; i++) {
    int c = tid + i * 256;
    int r = c >> 3, ds = (c & 7) * 8;
    GLOAD16(qb + (size_t)(q0 + r) * 64 + ds, PQ + c * 8);
  }
#pragma unroll
  for (int i = 0; i < 2; i++) {
    int c = tid + i * 256;
    int r = c >> 3, p = c & 7;
    GLOAD16(kb + (size_t)r * 64 + ((p ^ (r & 7)) * 8), Ks[0] + c * 8);
  }
#pragma unroll
  for (int i = 0; i < 2; i++) {
    int c = tid + i * 256;
    int r = c >> 3, p = c & 7;
    GLOAD16(vb + (size_t)r * 2048 + ((p ^ (r & 7)) * 8), Vs[0] + c * 8);
  }
  __syncthreads();   // drains all staging
  bf16x8 qf[2][2];   // B-operand frag: Q[q0+w32+m16+c16][ks*32+g*8..+8]
#pragma unroll
  for (int m = 0; m < 2; m++)
#pragma unroll
    for (int ks = 0; ks < 2; ks++)
      qf[m][ks] = *(const bf16x8*)(PQ + (w * 32 + m * 16 + c16) * 64 + ks * 32 + g * 8);
  __syncthreads();   // all waves done reading Qs (PQ becomes P storage)

  f32x4 o[2][4];
  float mrun[2], lrun[2];
  {
    f32x4 z = {0.f, 0.f, 0.f, 0.f};
#pragma unroll
    for (int m = 0; m < 2; m++) {
#pragma unroll
      for (int n = 0; n < 4; n++) o[m][n] = z;
      mrun[m] = -__builtin_inff();
      lrun[m] = 0.f;
    }
  }
  int qmax = q0 + w * 32 + 31;
  int nt = 2 * bx + 2;
  int cur = 0;

  for (int t = 0; t < nt; ++t) {
    int s0 = t * 64;
    // ---- prefetch next K/V tile into the other buffer ----
    if (t + 1 < nt) {
      int sn = s0 + 64;
#pragma unroll
      for (int i = 0; i < 2; i++) {
        int c = tid + i * 256;
        int r = c >> 3, p = c & 7;
        GLOAD16(kb + (size_t)(sn + r) * 64 + ((p ^ (r & 7)) * 8), Ks[cur ^ 1] + c * 8);
      }
#pragma unroll
      for (int i = 0; i < 2; i++) {
        int c = tid + i * 256;
        int r = c >> 3, p = c & 7;
        GLOAD16(vb + (size_t)r * 2048 + sn + ((p ^ (r & 7)) * 8), Vs[cur ^ 1] + c * 8);
      }
    }
    if (s0 <= qmax) {   // wave-uniform causal skip
      // ---- QK^T (swapped: A=K, B=Q -> lane holds S[q=c16][s=n*16+g4+r]) ----
      f32x4 S[2][4];
      {
        f32x4 z = {0.f, 0.f, 0.f, 0.f};
#pragma unroll
        for (int m = 0; m < 2; m++)
#pragma unroll
          for (int n = 0; n < 4; n++) S[m][n] = z;
      }
#pragma unroll
      for (int ks = 0; ks < 2; ks++) {
        bf16x8 kf[4];
#pragma unroll
        for (int n = 0; n < 4; n++) {
          int srow = n * 16 + c16;
          kf[n] = *(const bf16x8*)((const char*)Ks[cur] + srow * 128 +
                                   (((ks * 4 + g) ^ (srow & 7)) << 4));
        }
#pragma unroll
        for (int m = 0; m < 2; m++)
#pragma unroll
          for (int n = 0; n < 4; n++)
            S[m][n] = __builtin_amdgcn_mfma_f32_16x16x32_bf16(kf[n], qf[m][ks], S[m][n], 0, 0, 0);
      }
      // ---- per m-block: mask, online softmax, P write ----
#pragma unroll
      for (int m = 0; m < 2; m++) {
        int qbm = q0 + w * 32 + m * 16;
        int qr = qbm + c16;
        if (s0 + 63 > qbm) {   // wave-uniform
#pragma unroll
          for (int n = 0; n < 4; n++)
#pragma unroll
            for (int r = 0; r < 4; r++)
              if (s0 + n * 16 + g4 + r > qr) S[m][n][r] = -__builtin_inff();
        }
        float tm = S[m][0][0];
#pragma unroll
        for (int n = 0; n < 4; n++)
#pragma unroll
          for (int r = 0; r < 4; r++) tm = fmaxf(tm, S[m][n][r]);
        tm = fmaxf(tm, __shfl_xor(tm, 16));
        tm = fmaxf(tm, __shfl_xor(tm, 32));
        if (!__all(tm <= mrun[m] + 8.f)) {   // defer-max rescale (rare)
          float mnew = fmaxf(mrun[m], tm);
          float corr = __expf(mrun[m] - mnew);
          lrun[m] *= corr;
          mrun[m] = mnew;
#pragma unroll
          for (int j = 0; j < 4; j++) {
            float cj = __shfl(corr, (lane & 48) | (g4 + j));
#pragma unroll
            for (int n = 0; n < 4; n++) o[m][n][j] *= cj;
          }
        }
        float p[4][4];
        float rs = 0.f;
#pragma unroll
        for (int n = 0; n < 4; n++)
#pragma unroll
          for (int r = 0; r < 4; r++) {
            p[n][r] = __expf(S[m][n][r] - mrun[m]);
            rs += p[n][r];
          }
        rs += __shfl_xor(rs, 16);
        rs += __shfl_xor(rs, 32);
        lrun[m] += rs;
        // pack 4 bf16 and write (XOR-swizzled [16][64] tile per (wave,m))
        bf16* Pw = PQ + (w * 2 + m) * 1024;
#pragma unroll
        for (int n = 0; n < 4; n++) {
          bf16x4 pw;
          pw[0] = (bf16)p[n][0]; pw[1] = (bf16)p[n][1];
          pw[2] = (bf16)p[n][2]; pw[3] = (bf16)p[n][3];
          *(bf16x4*)(Pw + c16 * 64 + (((2 * n + (g >> 1)) ^ (c16 & 7)) * 8) + (g & 1) * 4) = pw;
        }
      }
      // ---- PV: A = P (q rows), B = V^T ----
#pragma unroll
      for (int ks = 0; ks < 2; ks++) {
        bf16x8 vf[4];
#pragma unroll
        for (int n = 0; n < 4; n++) {
          int drow = n * 16 + c16;
          vf[n] = *(const bf16x8*)((const char*)Vs[cur] + drow * 128 +
                                   (((ks * 4 + g) ^ (drow & 7)) << 4));
        }
        bf16x8 pf0 = *(const bf16x8*)(PQ + (w * 2 + 0) * 1024 + c16 * 64 + (((4 * ks + g) ^ (c16 & 7)) * 8));
        bf16x8 pf1 = *(const bf16x8*)(PQ + (w * 2 + 1) * 1024 + c16 * 64 + (((4 * ks + g) ^ (c16 & 7)) * 8));
#pragma unroll
        for (int n = 0; n < 4; n++)
          o[0][n] = __builtin_amdgcn_mfma_f32_16x16x32_bf16(pf0, vf[n], o[0][n], 0, 0, 0);
#pragma unroll
        for (int n = 0; n < 4; n++)
          o[1][n] = __builtin_amdgcn_mfma_f32_16x16x32_bf16(pf1, vf[n], o[1][n], 0, 0, 0);
      }
    }
    __syncthreads();   // drains prefetch (vmcnt 0) + protects buffer swap
    cur ^= 1;
  }
  // ---- epilogue: o row = m*16+g4+j, col = n*16+c16; lrun lives at c16=q ----
  int b = bh >> 4, h = bh & 15;
#pragma unroll
  for (int m = 0; m < 2; m++)
#pragma unroll
    for (int j = 0; j < 4; j++) {
      float lv = __shfl(lrun[m], (lane & 48) | (g4 + j));
      float inv = 1.f / lv;
      int t = q0 + w * 32 + m * 16 + g4 + j;
#pragma unroll
      for (int n = 0; n < 4; n++) {
        int col = h * 64 + n * 16 + c16;
        out[((size_t)(b * 2048 + t)) * 1024 + col] = (bf16)(o[m][n][j] * inv);
      }
    }
}

extern "C" void kernel_launch(void* const* d_in, const int* in_sizes, int n_in,
                              void* d_out, int out_size, void* d_ws, size_t ws_size,
                              hipStream_t stream) {
  const float* x    = (const float*)d_in[0];
  const float* Wqkv = (const float*)d_in[1];
  const float* Wout = (const float*)d_in[2];
  float* outp = (float*)d_out;
  char* ws = (char*)d_ws;
  const size_t MB = 1024 * 1024;
  bf16* xb    = (bf16*)(ws);             // 8 MB [4096][1024]; later reused as attn out
  bf16* wqkvT = (bf16*)(ws + 8 * MB);    // 6 MB [3072][1024]
  bf16* woutT = (bf16*)(ws + 14 * MB);   // 2 MB [1024][1024]
  bf16* qb    = (bf16*)(ws + 16 * MB);   // 8 MB [32][2048][64] (pre-scaled 1/8)
  bf16* kb    = (bf16*)(ws + 24 * MB);   // 8 MB [32][2048][64]
  bf16* vtb   = (bf16*)(ws + 32 * MB);   // 8 MB [32][64][2048]

  hipLaunchKernelGGL(cast_f32_bf16, dim3(2048), dim3(256), 0, stream,
                     x, xb, 4096 * 1024 / 8);
  hipLaunchKernelGGL(transpose_cast, dim3(96, 32), dim3(32, 8), 0, stream,
                     Wqkv, wqkvT, 1024, 3072);
  hipLaunchKernelGGL(transpose_cast, dim3(32, 32), dim3(32, 8), 0, stream,
                     Wout, woutT, 1024, 1024);
  hipLaunchKernelGGL(gemm_qkv, dim3(24, 32), dim3(256), 0, stream,
                     xb, wqkvT, qb, kb, vtb);
  hipLaunchKernelGGL(attn, dim3(16, 32), dim3(256), 0, stream,
                     qb, kb, vtb, xb);
  hipLaunchKernelGGL(gemm_out, dim3(8, 32), dim3(256), 0, stream,
                     xb, woutT, outp);
}

// Round 3
// 129.960 us; speedup vs baseline: 1.5379x; 1.1394x over previous
//
#include <hip/hip_runtime.h>
#include <hip/hip_bf16.h>

typedef __bf16 bf16;
typedef bf16 bf16x4 __attribute__((ext_vector_type(4)));
typedef bf16 bf16x8 __attribute__((ext_vector_type(8)));
typedef float f32x4 __attribute__((ext_vector_type(4)));

#define GLOAD16(g, l) __builtin_amdgcn_global_load_lds( \
    (const __attribute__((address_space(1))) void*)(g),  \
    (__attribute__((address_space(3))) void*)(l), 16, 0, 0)

#define EXP2F(x) __builtin_amdgcn_exp2f(x)

// ---------------- cast fp32 -> bf16, 8 elems/thread ----------------
__global__ __launch_bounds__(256) void cast_f32_bf16(const float* __restrict__ in,
                                                     bf16* __restrict__ out, int n8) {
  int i = blockIdx.x * 256 + threadIdx.x;
  if (i >= n8) return;
  const float4* p = (const float4*)in + (size_t)i * 2;
  float4 a = p[0], b = p[1];
  bf16x8 o;
  o[0] = (bf16)a.x; o[1] = (bf16)a.y; o[2] = (bf16)a.z; o[3] = (bf16)a.w;
  o[4] = (bf16)b.x; o[5] = (bf16)b.y; o[6] = (bf16)b.z; o[7] = (bf16)b.w;
  ((bf16x8*)out)[i] = o;
}

// ------------- transpose+cast: src[K][N] f32 -> dst[N][K] bf16 -------------
__global__ __launch_bounds__(256) void transpose_cast(const float* __restrict__ src,
                                                      bf16* __restrict__ dst,
                                                      int K, int N) {
  __shared__ float tile[32][33];
  int n0 = blockIdx.x * 32, k0 = blockIdx.y * 32;
  int tx = threadIdx.x, ty = threadIdx.y;  // 32 x 8
#pragma unroll
  for (int i = 0; i < 4; i++)
    tile[ty + 8 * i][tx] = src[(size_t)(k0 + ty + 8 * i) * N + n0 + tx];
  __syncthreads();
#pragma unroll
  for (int i = 0; i < 4; i++)
    dst[(size_t)(n0 + ty + 8 * i) * K + k0 + tx] = (bf16)tile[tx][ty + 8 * i];
}

// ---------------- GEMM mainloop: C[128,128] += A[M,K] * Bt[N,K]^T ----------
__device__ __forceinline__ void gemm_mainloop(const bf16* __restrict__ A,
                                              const bf16* __restrict__ Bt,
                                              int K, int m0, int n0,
                                              f32x4 acc[4][4],
                                              bf16* As, bf16* Bs) {
  int tid = threadIdx.x;
  int lane = tid & 63;
  int wave = tid >> 6;
  int wr = wave >> 1, wc = wave & 1;
  f32x4 z = {0.f, 0.f, 0.f, 0.f};
#pragma unroll
  for (int m = 0; m < 4; m++)
#pragma unroll
    for (int n = 0; n < 4; n++) acc[m][n] = z;
  int c16 = lane & 15;
  int ks8 = (lane >> 4) * 8;
  for (int k0 = 0; k0 < K; k0 += 32) {
#pragma unroll
    for (int i = 0; i < 2; i++) {
      int c = tid + i * 256;
      int r = c >> 2, ks = (c & 3) * 8;
      GLOAD16(A + (size_t)(m0 + r) * K + k0 + ks, As + c * 8);
    }
#pragma unroll
    for (int i = 0; i < 2; i++) {
      int c = tid + i * 256;
      int r = c >> 2, ks = (c & 3) * 8;
      GLOAD16(Bt + (size_t)(n0 + r) * K + k0 + ks, Bs + c * 8);
    }
    __syncthreads();
    bf16x8 af[4], bfr[4];
#pragma unroll
    for (int m = 0; m < 4; m++)
      af[m] = *(const bf16x8*)(As + (wr * 64 + m * 16 + c16) * 32 + ks8);
#pragma unroll
    for (int n = 0; n < 4; n++)
      bfr[n] = *(const bf16x8*)(Bs + (wc * 64 + n * 16 + c16) * 32 + ks8);
#pragma unroll
    for (int m = 0; m < 4; m++)
#pragma unroll
      for (int n = 0; n < 4; n++)
        acc[m][n] = __builtin_amdgcn_mfma_f32_16x16x32_bf16(af[m], bfr[n], acc[m][n], 0, 0, 0);
    __syncthreads();
  }
}

// ---- QKV GEMM: x[4096,1024] @ WqkvT[3072,1024]^T -> q,k scaled / vT scatter ----
// q is pre-scaled by (1/8)*log2(e) so attention softmax can run in exp2 domain.
__global__ __launch_bounds__(256) void gemm_qkv(const bf16* __restrict__ A,
                                                const bf16* __restrict__ Bt,
                                                bf16* __restrict__ q,
                                                bf16* __restrict__ kk,
                                                bf16* __restrict__ vt) {
  __shared__ bf16 As[128 * 32];
  __shared__ bf16 Bs[128 * 32];
  int m0 = blockIdx.y * 128, n0 = blockIdx.x * 128;
  f32x4 acc[4][4];
  gemm_mainloop(A, Bt, 1024, m0, n0, acc, As, Bs);
  int lane = threadIdx.x & 63;
  int wave = threadIdx.x >> 6;
  int wr = wave >> 1, wc = wave & 1;
  int which = n0 >> 10;
  const float QSCALE = 0.125f * 1.4426950408889634f;
#pragma unroll
  for (int m = 0; m < 4; m++)
#pragma unroll
    for (int n = 0; n < 4; n++)
#pragma unroll
      for (int j = 0; j < 4; j++) {
        int gm = m0 + wr * 64 + m * 16 + (lane >> 4) * 4 + j;
        int gn = n0 + wc * 64 + n * 16 + (lane & 15);
        int rem = gn & 1023;
        int h = rem >> 6, d = rem & 63;
        int b = gm >> 11, t = gm & 2047;
        float v = acc[m][n][j];
        size_t bh = (size_t)(b * 16 + h);
        if (which == 0)      q[(bh * 2048 + t) * 64 + d]  = (bf16)(v * QSCALE);
        else if (which == 1) kk[(bh * 2048 + t) * 64 + d] = (bf16)v;
        else                 vt[(bh * 64 + d) * 2048 + t] = (bf16)v;
      }
}

// ---- final GEMM: attn[4096,1024] @ WoutT[1024,1024]^T -> out fp32 ----
__global__ __launch_bounds__(256) void gemm_out(const bf16* __restrict__ A,
                                                const bf16* __restrict__ Bt,
                                                float* __restrict__ C) {
  __shared__ bf16 As[128 * 32];
  __shared__ bf16 Bs[128 * 32];
  int m0 = blockIdx.y * 128, n0 = blockIdx.x * 128;
  f32x4 acc[4][4];
  gemm_mainloop(A, Bt, 1024, m0, n0, acc, As, Bs);
  int lane = threadIdx.x & 63;
  int wave = threadIdx.x >> 6;
  int wr = wave >> 1, wc = wave & 1;
#pragma unroll
  for (int m = 0; m < 4; m++)
#pragma unroll
    for (int n = 0; n < 4; n++)
#pragma unroll
      for (int j = 0; j < 4; j++) {
        int gm = m0 + wr * 64 + m * 16 + (lane >> 4) * 4 + j;
        int gn = n0 + wc * 64 + n * 16 + (lane & 15);
        C[(size_t)gm * 1024 + gn] = acc[m][n][j];
      }
}

// ---------------- flash attention v3 ----------------
// 512 blocks x 512 threads (8 waves); wave w owns q rows [q0+16w, +16).
// Swapped QK^T (S^T = mfma(K,Q)); softmax in exp2 domain, in-register,
// 2 shuffles per reduce; defer-max (THR=8). K/V double-buffered, XOR-swizzled
// (pre-swizzled global source, linear LDS dest). XCD-aware block decode:
// XCD c = id&7 owns bh in [4c,4c+4) (K/V 2MB -> L2-resident, 16x reuse);
// blocks paired (k, k+32) with q-tile indices summing to 15.
__global__ __launch_bounds__(512) void attn(const bf16* __restrict__ q,
                                            const bf16* __restrict__ kk,
                                            const bf16* __restrict__ vt,
                                            bf16* __restrict__ out) {
  __shared__ bf16 Ks[2][64 * 64];   // 16 KB (chunk-XOR swizzled)
  __shared__ bf16 Vs[2][64 * 64];   // 16 KB (chunk-XOR swizzled)
  __shared__ bf16 PQ[128 * 64];     // 16 KB: Q staging (prologue) / P tiles (loop)
  int tid = threadIdx.x, lane = tid & 63, w = tid >> 6;
  int c16 = lane & 15, g = (lane >> 4) & 3, g4 = g * 4;

  // ---- XCD-aware decode (bijection on 512 blocks) ----
  int id = blockIdx.x;
  int c = id & 7;          // XCD (assumes id%8 round-robin)
  int k = id >> 3;         // 0..63 within XCD
  int s = k >> 5;          // 0..1
  int j5 = k & 31;
  int bxi = j5 & 15, b2 = j5 >> 4;
  int bx = s ? (15 - bxi) : bxi;       // pairs (k, k+32) sum to 15
  int bh = 4 * c + 2 * b2 + s;         // 4 bh per XCD
  int q0 = bx * 128;

  const bf16* qb = q  + (size_t)bh * 2048 * 64;
  const bf16* kb = kk + (size_t)bh * 2048 * 64;
  const bf16* vb = vt + (size_t)bh * 64 * 2048;

  // ---- prologue: stage Q[128][64] (2 chunks/thr) and K/V tile 0 (1 each) ----
#pragma unroll
  for (int i = 0; i < 2; i++) {
    int cc = tid + i * 512;
    int r = cc >> 3, ds = (cc & 7) * 8;
    GLOAD16(qb + (size_t)(q0 + r) * 64 + ds, PQ + cc * 8);
  }
  {
    int r = tid >> 3, p = tid & 7;
    GLOAD16(kb + (size_t)r * 64 + ((p ^ (r & 7)) * 8), Ks[0] + tid * 8);
    GLOAD16(vb + (size_t)r * 2048 + ((p ^ (r & 7)) * 8), Vs[0] + tid * 8);
  }
  __syncthreads();
  bf16x8 qf[2];   // B-operand frag: Q[q0+16w+c16][ks*32+g*8 ..]
#pragma unroll
  for (int ks = 0; ks < 2; ks++)
    qf[ks] = *(const bf16x8*)(PQ + (w * 16 + c16) * 64 + ks * 32 + g * 8);
  __syncthreads();   // all waves done reading Q (PQ becomes P storage)

  f32x4 o[4];
  float mrun = -__builtin_inff(), lrun = 0.f;
  {
    f32x4 z = {0.f, 0.f, 0.f, 0.f};
#pragma unroll
    for (int n = 0; n < 4; n++) o[n] = z;
  }
  int qlo = q0 + w * 16;           // first q row of this wave
  int qr = qlo + c16;              // this lane's q row
  int nt = 2 * bx + 2;
  int cur = 0;
  bf16* Pw = PQ + w * 1024;        // 16x64 per-wave P tile

  for (int t = 0; t < nt; ++t) {
    int s0 = t * 64;
    // ---- prefetch next K/V tile into the other buffer ----
    if (t + 1 < nt) {
      int sn = s0 + 64;
      int r = tid >> 3, p = tid & 7;
      GLOAD16(kb + (size_t)(sn + r) * 64 + ((p ^ (r & 7)) * 8), Ks[cur ^ 1] + tid * 8);
      GLOAD16(vb + (size_t)r * 2048 + sn + ((p ^ (r & 7)) * 8), Vs[cur ^ 1] + tid * 8);
    }
    if (s0 <= qlo + 15) {   // wave-uniform causal skip
      // ---- QK^T: S^T = mfma(K, Q); lane holds S[q=c16][s=n*16+g4+r] ----
      f32x4 S[4];
      {
        f32x4 z = {0.f, 0.f, 0.f, 0.f};
#pragma unroll
        for (int n = 0; n < 4; n++) S[n] = z;
      }
      __builtin_amdgcn_s_setprio(1);
#pragma unroll
      for (int ks = 0; ks < 2; ks++) {
        bf16x8 kf[4];
#pragma unroll
        for (int n = 0; n < 4; n++) {
          int srow = n * 16 + c16;
          kf[n] = *(const bf16x8*)((const char*)Ks[cur] + srow * 128 +
                                   (((ks * 4 + g) ^ (srow & 7)) << 4));
        }
#pragma unroll
        for (int n = 0; n < 4; n++)
          S[n] = __builtin_amdgcn_mfma_f32_16x16x32_bf16(kf[n], qf[ks], S[n], 0, 0, 0);
      }
      __builtin_amdgcn_s_setprio(0);
      // ---- causal mask (diag tiles only, wave-uniform test) ----
      if (s0 + 63 > qlo) {
#pragma unroll
        for (int n = 0; n < 4; n++)
#pragma unroll
          for (int r = 0; r < 4; r++)
            if (s0 + n * 16 + g4 + r > qr) S[n][r] = -__builtin_inff();
      }
      // ---- online softmax (exp2 domain), defer-max ----
      float tm = fmaxf(fmaxf(fmaxf(S[0][0], S[0][1]), fmaxf(S[0][2], S[0][3])),
                       fmaxf(fmaxf(S[1][0], S[1][1]), fmaxf(S[1][2], S[1][3])));
      tm = fmaxf(tm, fmaxf(fmaxf(fmaxf(S[2][0], S[2][1]), fmaxf(S[2][2], S[2][3])),
                           fmaxf(fmaxf(S[3][0], S[3][1]), fmaxf(S[3][2], S[3][3]))));
      tm = fmaxf(tm, __shfl_xor(tm, 16));
      tm = fmaxf(tm, __shfl_xor(tm, 32));
      if (!__all(tm <= mrun + 8.f)) {   // rescale (rare after first tile)
        float mnew = fmaxf(mrun, tm);
        float corr = EXP2F(mrun - mnew);
        lrun *= corr;
        mrun = mnew;
#pragma unroll
        for (int j = 0; j < 4; j++) {
          float cj = __shfl(corr, (lane & 48) | (g4 + j));
#pragma unroll
          for (int n = 0; n < 4; n++) o[n][j] *= cj;
        }
      }
      float p[4][4];
      float rs = 0.f;
#pragma unroll
      for (int n = 0; n < 4; n++)
#pragma unroll
        for (int r = 0; r < 4; r++) {
          p[n][r] = EXP2F(S[n][r] - mrun);
          rs += p[n][r];
        }
      rs += __shfl_xor(rs, 16);
      rs += __shfl_xor(rs, 32);
      lrun += rs;
      // ---- pack P to LDS (XOR-swizzled [16][64] per-wave tile) ----
#pragma unroll
      for (int n = 0; n < 4; n++) {
        bf16x4 pw;
        pw[0] = (bf16)p[n][0]; pw[1] = (bf16)p[n][1];
        pw[2] = (bf16)p[n][2]; pw[3] = (bf16)p[n][3];
        *(bf16x4*)(Pw + c16 * 64 + (((2 * n + (g >> 1)) ^ (c16 & 7)) * 8) + (g & 1) * 4) = pw;
      }
      // ---- PV: o[q][d] += P[q][s] V^T[d][s]^T ----
      __builtin_amdgcn_s_setprio(1);
#pragma unroll
      for (int ks = 0; ks < 2; ks++) {
        bf16x8 vf[4];
#pragma unroll
        for (int n = 0; n < 4; n++) {
          int drow = n * 16 + c16;
          vf[n] = *(const bf16x8*)((const char*)Vs[cur] + drow * 128 +
                                   (((ks * 4 + g) ^ (drow & 7)) << 4));
        }
        bf16x8 pf = *(const bf16x8*)(Pw + c16 * 64 + (((ks * 4 + g) ^ (c16 & 7)) * 8));
#pragma unroll
        for (int n = 0; n < 4; n++)
          o[n] = __builtin_amdgcn_mfma_f32_16x16x32_bf16(pf, vf[n], o[n], 0, 0, 0);
      }
      __builtin_amdgcn_s_setprio(0);
    }
    __syncthreads();   // drains prefetch + protects buffer swap
    cur ^= 1;
  }
  // ---- epilogue: o row q = qlo+g4+j, col d = n*16+c16 ----
  int b = bh >> 4, h = bh & 15;
#pragma unroll
  for (int j = 0; j < 4; j++) {
    float lv = __shfl(lrun, (lane & 48) | (g4 + j));
    float inv = 1.f / lv;
    int t = qlo + g4 + j;
#pragma unroll
    for (int n = 0; n < 4; n++) {
      int col = h * 64 + n * 16 + c16;
      out[((size_t)(b * 2048 + t)) * 1024 + col] = (bf16)(o[n][j] * inv);
    }
  }
}

extern "C" void kernel_launch(void* const* d_in, const int* in_sizes, int n_in,
                              void* d_out, int out_size, void* d_ws, size_t ws_size,
                              hipStream_t stream) {
  const float* x    = (const float*)d_in[0];
  const float* Wqkv = (const float*)d_in[1];
  const float* Wout = (const float*)d_in[2];
  float* outp = (float*)d_out;
  char* ws = (char*)d_ws;
  const size_t MB = 1024 * 1024;
  bf16* xb    = (bf16*)(ws);             // 8 MB [4096][1024]; later reused as attn out
  bf16* wqkvT = (bf16*)(ws + 8 * MB);    // 6 MB [3072][1024]
  bf16* woutT = (bf16*)(ws + 14 * MB);   // 2 MB [1024][1024]
  bf16* qb    = (bf16*)(ws + 16 * MB);   // 8 MB [32][2048][64] (scaled 0.125*log2e)
  bf16* kb    = (bf16*)(ws + 24 * MB);   // 8 MB [32][2048][64]
  bf16* vtb   = (bf16*)(ws + 32 * MB);   // 8 MB [32][64][2048]

  hipLaunchKernelGGL(cast_f32_bf16, dim3(2048), dim3(256), 0, stream,
                     x, xb, 4096 * 1024 / 8);
  hipLaunchKernelGGL(transpose_cast, dim3(96, 32), dim3(32, 8), 0, stream,
                     Wqkv, wqkvT, 1024, 3072);
  hipLaunchKernelGGL(transpose_cast, dim3(32, 32), dim3(32, 8), 0, stream,
                     Wout, woutT, 1024, 1024);
  hipLaunchKernelGGL(gemm_qkv, dim3(24, 32), dim3(256), 0, stream,
                     xb, wqkvT, qb, kb, vtb);
  hipLaunchKernelGGL(attn, dim3(512), dim3(512), 0, stream,
                     qb, kb, vtb, xb);
  hipLaunchKernelGGL(gemm_out, dim3(8, 32), dim3(256), 0, stream,
                     xb, woutT, outp);
}